// Round 1
// baseline (298.261 us; speedup 1.0000x reference)
//
#include <hip/hip_runtime.h>

typedef unsigned short u16;
typedef __bf16 bf16;
typedef __attribute__((ext_vector_type(8))) __bf16 bf16x8;  // MFMA A/B frag (4 VGPRs)
typedef __attribute__((ext_vector_type(4))) float f32x4;    // MFMA C/D frag

#define AS1(p) ((const __attribute__((address_space(1))) void*)(p))
#define AS3(p) ((__attribute__((address_space(3))) void*)(p))

__device__ __forceinline__ u16 f2bf(float f) {
  unsigned u = __builtin_bit_cast(unsigned, f);
  u += 0x7fffu + ((u >> 16) & 1u);
  return (u16)(u >> 16);
}

static constexpr int  B_ = 2, N_ = 2048, C_ = 1024, H_ = 8, DH_ = 128;
static constexpr long SZ_IN = (long)B_ * N_ * C_;  // 4,194,304 elems
static constexpr long SZ_W  = (long)C_ * C_;       // 1,048,576 elems

// ---------------------------------------------------------------------------
// Fused cast kernel: y=0/1 -> input fp32->bf16 cast; y=2 -> weight
// cast+transpose (x<1024: matrix z=x>>8, 64x64 tile = x&255). One launch
// instead of two (fewer launch gaps; paths are block-uniform).
// ---------------------------------------------------------------------------
__global__ void k_cast(const float* __restrict__ q, const float* __restrict__ kv,
                       const float* __restrict__ W0, const float* __restrict__ W1,
                       const float* __restrict__ W2, const float* __restrict__ W3,
                       u16* __restrict__ qb, u16* __restrict__ kvb,
                       u16* __restrict__ WT)
{
  __shared__ u16 t[64][65];
  int tid = threadIdx.x;
  if (blockIdx.y < 2) {
    const float* src = blockIdx.y ? kv : q;
    u16* dst = blockIdx.y ? kvb : qb;
    long i = ((long)blockIdx.x * 256 + tid) * 8;
    float4 a = *(const float4*)(src + i);
    float4 b = *(const float4*)(src + i + 4);
    uint4 v;
    v.x = f2bf(a.x) | ((unsigned)f2bf(a.y) << 16);
    v.y = f2bf(a.z) | ((unsigned)f2bf(a.w) << 16);
    v.z = f2bf(b.x) | ((unsigned)f2bf(b.y) << 16);
    v.w = f2bf(b.z) | ((unsigned)f2bf(b.w) << 16);
    *(uint4*)(dst + i) = v;
    return;
  }
  int x = blockIdx.x;
  if (x >= 1024) return;
  int z = x >> 8, tile = x & 255;
  const float* W = (z == 0) ? W0 : (z == 1) ? W1 : (z == 2) ? W2 : W3;
  u16* dst = WT + (long)z * SZ_W;
  int n0 = (tile & 15) * 64, k0 = (tile >> 4) * 64;
#pragma unroll
  for (int r = 0; r < 4; ++r) {
    int slot = r * 256 + tid;
    int row = slot >> 4, c4 = slot & 15;
    float4 a = *(const float4*)(W + (long)(k0 + row) * 1024 + n0 + c4 * 4);
    t[c4*4+0][row] = f2bf(a.x);
    t[c4*4+1][row] = f2bf(a.y);
    t[c4*4+2][row] = f2bf(a.z);
    t[c4*4+3][row] = f2bf(a.w);
  }
  __syncthreads();
#pragma unroll
  for (int r = 0; r < 4; ++r) {
    int slot = r * 256 + tid;
    int row = slot >> 4, c4 = slot & 15;
    uint2 v;
    v.x = t[row][c4*4+0] | ((unsigned)t[row][c4*4+1] << 16);
    v.y = t[row][c4*4+2] | ((unsigned)t[row][c4*4+3] << 16);
    *(uint2*)(dst + (long)(n0 + row) * 1024 + k0 + c4 * 4) = v;
  }
}

// ---------------------------------------------------------------------------
// m97-style GEMM mainloop with XOR bank swizzle (round-2-proven, unchanged).
// ---------------------------------------------------------------------------
__device__ __forceinline__ void gemm_main_128x128(
    const u16* __restrict__ A, const u16* __restrict__ BT,
    u16* lA, u16* lB, int m0, int n0, int tid, f32x4 acc[4][4])
{
  int w = tid >> 6, l = tid & 63, quad = l >> 4, lm = l & 15;
  int wm = w >> 1, wn = w & 1;
  int srow = tid >> 2, schunk = tid & 3;
  int sxw = (srow >> 1) & 3;
  int sxr = (lm >> 1) & 3;
  const u16* Ag = A + (long)(m0 + srow) * 1024 + (schunk ^ sxw) * 8;
  const u16* Bg = BT + (long)(n0 + srow) * 1024 + (schunk ^ sxw) * 8;
  u16* lAw = lA + w * 512;
  u16* lBw = lB + w * 512;
  for (int kb = 0; kb < 32; ++kb) {
    const u16* Agk = Ag + kb * 32;
    const u16* Bgk = Bg + kb * 32;
    __builtin_amdgcn_global_load_lds(AS1(Agk),           AS3(lAw),        16, 0, 0);
    __builtin_amdgcn_global_load_lds(AS1(Agk + 64*1024), AS3(lAw + 2048), 16, 0, 0);
    __builtin_amdgcn_global_load_lds(AS1(Bgk),           AS3(lBw),        16, 0, 0);
    __builtin_amdgcn_global_load_lds(AS1(Bgk + 64*1024), AS3(lBw + 2048), 16, 0, 0);
    __syncthreads();
    bf16x8 af[4], bfr[4];
#pragma unroll
    for (int mi = 0; mi < 4; ++mi)
      af[mi] = *(const bf16x8*)(lA + (wm*64 + mi*16 + lm)*32 + ((quad ^ sxr))*8);
#pragma unroll
    for (int ni = 0; ni < 4; ++ni)
      bfr[ni] = *(const bf16x8*)(lB + (wn*64 + ni*16 + lm)*32 + ((quad ^ sxr))*8);
#pragma unroll
    for (int mi = 0; mi < 4; ++mi)
#pragma unroll
      for (int ni = 0; ni < 4; ++ni)
        acc[mi][ni] = __builtin_amdgcn_mfma_f32_16x16x32_bf16(af[mi], bfr[ni], acc[mi][ni], 0, 0, 0);
    __syncthreads();
  }
}

// ---------------------------------------------------------------------------
// QKV projection v2 (unchanged, r6/r7-proven).
// ---------------------------------------------------------------------------
__global__ __launch_bounds__(256, 3)
void k_gemm_qkv(const u16* __restrict__ qb, const u16* __restrict__ kvb,
                const u16* __restrict__ wt,
                const float* __restrict__ bq, const float* __restrict__ bk,
                const float* __restrict__ bv,
                u16* __restrict__ Qb, u16* __restrict__ Kb, u16* __restrict__ VTb)
{
  __shared__ u16 lA[4096], lB[4096];
  int tid = threadIdx.x;
  int z = blockIdx.z;
  f32x4 acc[4][4] = {};
  int w = tid >> 6, l = tid & 63, quad = l >> 4, lm = l & 15;
  int wm = w >> 1, wn = w & 1;

  if (z == 2) {
    int m0 = blockIdx.y * 128, n0 = blockIdx.x * 128;
    gemm_main_128x128(kvb, wt + 2 * SZ_W, lA, lB, m0, n0, tid, acc);
#pragma unroll
    for (int ni = 0; ni < 4; ++ni) {
      int n = n0 + wn*64 + ni*16 + lm;       // channel
      float bb = bv[n];
      int h = n >> 7, dd = n & 127;
#pragma unroll
      for (int mi = 0; mi < 4; ++mi) {
        int mbase = m0 + wm*64 + mi*16 + quad*4;  // token (4 consecutive)
        int bidx = mbase >> 11, nn = mbase & 2047;
        u16 o0 = f2bf(acc[mi][ni][0] + bb), o1 = f2bf(acc[mi][ni][1] + bb);
        u16 o2 = f2bf(acc[mi][ni][2] + bb), o3 = f2bf(acc[mi][ni][3] + bb);
        uint2 v; v.x = o0 | ((unsigned)o1 << 16); v.y = o2 | ((unsigned)o3 << 16);
        *(uint2*)(VTb + ((long)(bidx*8 + h)*128 + dd)*2048 + nn) = v;
      }
    }
  } else {
    const u16* X = (z == 0) ? qb : kvb;
    const float* bias = (z == 0) ? bq : bk;
    u16* dst = (z == 0) ? Qb : Kb;
    float scale = (z == 0) ? 0.08838834764831845f : 1.0f;  // fold 1/sqrt(128)
    int m0 = blockIdx.x * 128, n0 = blockIdx.y * 128;
    gemm_main_128x128(wt + (long)z * SZ_W, X, lA, lB, m0, n0, tid, acc);
#pragma unroll
    for (int mi = 0; mi < 4; ++mi) {
      int chb = m0 + wm*64 + mi*16 + quad*4;   // channel base (4 consecutive)
      int h = chb >> 7, d = chb & 127;
      float4 bb = *(const float4*)(bias + chb);
#pragma unroll
      for (int ni = 0; ni < 4; ++ni) {
        int tok = n0 + wn*64 + ni*16 + lm;
        int bidx = tok >> 11, nn = tok & 2047;
        u16 o0 = f2bf((acc[mi][ni][0] + bb.x) * scale);
        u16 o1 = f2bf((acc[mi][ni][1] + bb.y) * scale);
        u16 o2 = f2bf((acc[mi][ni][2] + bb.z) * scale);
        u16 o3 = f2bf((acc[mi][ni][3] + bb.w) * scale);
        uint2 v; v.x = o0 | ((unsigned)o1 << 16); v.y = o2 | ((unsigned)o3 << 16);
        *(uint2*)(dst + ((long)(bidx*8 + h)*2048 + nn)*128 + d) = v;
      }
    }
  }
}

// ---------------------------------------------------------------------------
// Flash attention v9 — occupancy doubling via shared K-tile streams.
//
// v8 (88.7us): 2-wave blocks, each wave PRIVATELY double-buffers its key-half
// tiles -> 32KB of the 37KB LDS -> 4 blocks/CU -> 2 waves/SIMD. Counters
// (MfmaUtil 15.4, VALUBusy 22.7, HBM 3%, Occ 20.5) = latency-bound: at 2
// waves/SIMD the kf lgkmcnt wait, P round-trip, and exp chain have only one
// other wave to hide behind.
//
// v9: 4-wave blocks (256 thr). Wave (wk,wq): wk = key half (32 tiles of 32,
// unchanged), wq = q sub-tile (16 of the block's 32 q-rows). The two wq waves
// of a wk pair SHARE the staged K tile (each issues 4 of the 8 DMA chunks).
// Same LDS (K 32KB + P 4x1KB + stats = 37.1KB), same grid (16,64), same
// barrier/DMA pipeline, but 4 blocks/CU x 4 waves = 16 waves/CU = 4/SIMD.
// Per-wave state halves (qf 16, accO 32 regs) -> fits the 128-VGPR cap of
// __launch_bounds__(256,4). Cost: wq pair duplicates V fragment loads
// (L2-resident, ~20 TB/s of 34.5 ceiling). Merge is per-wq pair: wk=1 parks
// unnormalized O (16KB f32, overlays bufK), wk=0 combines.
// LDS u16 layout: bufK [0,16384) (wk*2+buf)*4096 | lP [16384,18432) w*512
// | lStat [18432,18560) [w][16] f32.
// ---------------------------------------------------------------------------
__global__ __launch_bounds__(256, 4)
void k_attn(const u16* __restrict__ Qb, const u16* __restrict__ Kb,
            const u16* __restrict__ VTb, u16* __restrict__ Sout)
{
  __shared__ u16 smem[18560];   // 37120 B -> 4 blocks/CU
  u16*   lP    = smem + 16384;
  float* lStat = (float*)(smem + 18432);  // [4 waves][16 q]

  int tid = threadIdx.x;
  int w = tid >> 6, l = tid & 63, quad = l >> 4, lm = l & 15;
  int wk = w >> 1;                 // key half
  int wq = w & 1;                  // q sub-tile (16 rows)
  int bh = blockIdx.x;             // XCD = bh % 8 -> 2 bh per XCD L2
  int q0 = blockIdx.y * 32;
  const u16* Qg = Qb + ((long)bh * 2048 + q0 + wq * 16) * 128;
  const u16* Kg = Kb + (long)bh * 2048 * 128;
  const u16* Vg = VTb + (long)bh * 128 * 2048;
  u16* lPw = lP + w * 512;

  // register-resident Q (16 q-rows, DH=128), scale pre-folded at projection
  bf16x8 qf[4];
#pragma unroll
  for (int kk = 0; kk < 4; ++kk)
    qf[kk] = *(const bf16x8*)(Qg + (long)lm * 128 + kk*32 + quad*8);

  f32x4 accO[8] = {};
  float sumP[4] = {};

  // K tile staging: 32 keys x 128 d = 512 x 16B chunks, staged cooperatively
  // by the wk pair (each wave 4 DMA insts, pair-lane lp = wq*64+l).
  // Chunk swizzle c^(r&7) -> kf reads 2-way max.
  auto stage = [&](int tt) {
    u16* dstb = smem + (wk*2 + (tt & 1)) * 4096;
#pragma unroll
    for (int j = 0; j < 4; ++j) {
      int s = j*128 + wq*64 + l;
      int r = s >> 4, c = s & 15;
      __builtin_amdgcn_global_load_lds(
          AS1(Kg + (long)(wk*1024 + tt*32 + r)*128 + ((c ^ (r & 7)) * 8)),
          AS3(dstb + j*1024 + wq*512), 16, 0, 0);
    }
  };

  stage(0);

#pragma unroll 1
  for (int t = 0; t < 32; ++t) {
    __syncthreads();          // drains stage(t) DMA; WAR-protects buf (t+1)&1
    stage(t + 1);             // t=31: prefetch runs past this head's K (ws, benign)

    int k0 = wk*1024 + t*32;
    // V fragments direct from global (L2-resident; consumed after QK^T+softmax)
    bf16x8 vf[8];
#pragma unroll
    for (int ni = 0; ni < 8; ++ni)
      vf[ni] = *(const bf16x8*)(Vg + (long)(ni*16 + lm)*2048 + k0 + quad*8);

    // QK^T: 16q x 32k from the PREFETCHED (shared) LDS buffer
    const u16* bk = smem + (wk*2 + (t & 1)) * 4096;
    f32x4 accS[2] = {};
#pragma unroll
    for (int kk = 0; kk < 4; ++kk)
#pragma unroll
      for (int ni = 0; ni < 2; ++ni) {
        bf16x8 kf = *(const bf16x8*)(bk + ((ni*16 + lm)*16 + (((kk*4 + quad) ^ (lm & 7))))*8);
        accS[ni] = __builtin_amdgcn_mfma_f32_16x16x32_bf16(qf[kk], kf, accS[ni], 0, 0, 0);
      }

    // no-max softmax: p = exp(s); per-lane partial sums; P -> swizzled LDS
#pragma unroll
    for (int r = 0; r < 4; ++r) {
      int R = quad*4 + r;
      int xr = (quad*2 + (r >> 1)) & 3;
#pragma unroll
      for (int ni = 0; ni < 2; ++ni) {
        float p = __expf(accS[ni][r]);
        sumP[r] += p;
        int ch = ni*2 + (lm >> 3);
        lPw[(R*4 + (ch ^ xr))*8 + (lm & 7)] = f2bf(p);
      }
    }

    // P A-frag (own wave's LDS region; compiler inserts lgkmcnt wait)
    bf16x8 pf = *(const bf16x8*)(lPw + (lm*4 + (quad ^ ((lm >> 1) & 3)))*8);

    // O += P V
#pragma unroll
    for (int ni = 0; ni < 8; ++ni)
      accO[ni] = __builtin_amdgcn_mfma_f32_16x16x32_bf16(pf, vf[ni], accO[ni], 0, 0, 0);
  }

  // ---- row-sum reduce (16 col-lanes per row) + publish stats ----
#pragma unroll
  for (int r = 0; r < 4; ++r) {
    float s = sumP[r];
    s += __shfl_xor(s, 1);
    s += __shfl_xor(s, 2);
    s += __shfl_xor(s, 4);
    s += __shfl_xor(s, 8);
    lStat[w*16 + quad*4 + r] = s;   // 16 lanes same val: benign
  }

  // ---- wq-pair merge: wk=1 parks unnormalized O in LDS, wk=0 combines ----
  float* lO = (float*)smem;   // [32 q][128 d] f32 = 16 KB, overlays bufK
  __syncthreads();            // drains stage(32) DMA; lStat visible
  if (wk == 1) {
#pragma unroll
    for (int ni = 0; ni < 8; ++ni)
#pragma unroll
      for (int r = 0; r < 4; ++r)
        lO[(wq*16 + quad*4 + r)*128 + ni*16 + lm] = accO[ni][r];
  }
  __syncthreads();
  if (wk == 0) {
    int b = bh >> 3, h = bh & 7;
#pragma unroll
    for (int r = 0; r < 4; ++r) {
      int R = quad*4 + r;            // row within this wq's 16
      int Rg = wq*16 + R;            // row within the block's 32
      float linv = 1.f / (lStat[wq*16 + R] + lStat[(2 + wq)*16 + R]);
#pragma unroll
      for (int ni = 0; ni < 8; ++ni) {
        float v = (accO[ni][r] + lO[Rg*128 + ni*16 + lm]) * linv;
        Sout[((long)(b*2048 + q0 + Rg))*1024 + h*128 + ni*16 + lm] = f2bf(v);
      }
    }
  }
}

// ---------------------------------------------------------------------------
// Output projection v2 (unchanged, r6/r7-proven).
// ---------------------------------------------------------------------------
__global__ __launch_bounds__(256, 3)
void k_gemm_out(const u16* __restrict__ S, const u16* __restrict__ WoT,
                const float* __restrict__ bo, float* __restrict__ out)
{
  __shared__ u16 lA[4096], lB[4096];
  int tid = threadIdx.x;
  int m0 = blockIdx.x * 128, n0 = blockIdx.y * 128;   // m = channel, n = token
  f32x4 acc[4][4] = {};
  gemm_main_128x128(WoT, S, lA, lB, m0, n0, tid, acc);

  int w = tid >> 6, l = tid & 63, quad = l >> 4, lm = l & 15;
  int wm = w >> 1, wn = w & 1;
#pragma unroll
  for (int mi = 0; mi < 4; ++mi) {
    int chb = m0 + wm*64 + mi*16 + quad*4;   // 4 consecutive channels
    float4 bb = *(const float4*)(bo + chb);
#pragma unroll
    for (int ni = 0; ni < 4; ++ni) {
      int tok = n0 + wn*64 + ni*16 + lm;
      float4 v;
      v.x = acc[mi][ni][0] + bb.x;
      v.y = acc[mi][ni][1] + bb.y;
      v.z = acc[mi][ni][2] + bb.z;
      v.w = acc[mi][ni][3] + bb.w;
      *(float4*)(out + (long)tok * 1024 + chb) = v;
    }
  }
}

// ---------------------------------------------------------------------------
// ws layout (u16 elems), 48 MiB: ABUF (q_bf16, reused for summed), KVB,
// WT 4x, Qb/Kb [b][h][n][d], VTb [b][h][d][n]
// ---------------------------------------------------------------------------
extern "C" void kernel_launch(void* const* d_in, const int* in_sizes, int n_in,
                              void* d_out, int out_size, void* d_ws, size_t ws_size,
                              hipStream_t stream)
{
  const float* inq  = (const float*)d_in[0];
  const float* inkv = (const float*)d_in[1];
  const float* Wq = (const float*)d_in[2];
  const float* bq = (const float*)d_in[3];
  const float* Wk = (const float*)d_in[4];
  const float* bk = (const float*)d_in[5];
  const float* Wv = (const float*)d_in[6];
  const float* bv = (const float*)d_in[7];
  const float* Wo = (const float*)d_in[8];
  const float* bo = (const float*)d_in[9];

  u16* ws   = (u16*)d_ws;
  u16* ABUF = ws;
  u16* KVB  = ws + SZ_IN;
  u16* WT   = ws + 2 * SZ_IN;
  u16* Qb   = WT + 4 * SZ_W;
  u16* Kb   = Qb + SZ_IN;
  u16* VTb  = Kb + SZ_IN;

  k_cast    <<<dim3(2048, 3),   256, 0, stream>>>(inq, inkv, Wq, Wk, Wv, Wo, ABUF, KVB, WT);
  k_gemm_qkv<<<dim3(8, 32, 3),  256, 0, stream>>>(ABUF, KVB, WT, bq, bk, bv, Qb, Kb, VTb);
  k_attn    <<<dim3(16, 64),    256, 0, stream>>>(Qb, Kb, VTb, ABUF);
  k_gemm_out<<<dim3(8, 32),     256, 0, stream>>>(ABUF, WT + 3 * SZ_W, bo, (float*)d_out);
}

// Round 2
// 242.902 us; speedup vs baseline: 1.2279x; 1.2279x over previous
//
#include <hip/hip_runtime.h>

typedef unsigned short u16;
typedef __bf16 bf16;
typedef __attribute__((ext_vector_type(8))) __bf16 bf16x8;  // MFMA A/B frag (4 VGPRs)
typedef __attribute__((ext_vector_type(4))) float f32x4;    // MFMA C/D frag

#define AS1(p) ((const __attribute__((address_space(1))) void*)(p))
#define AS3(p) ((__attribute__((address_space(3))) void*)(p))

__device__ __forceinline__ u16 f2bf(float f) {
  unsigned u = __builtin_bit_cast(unsigned, f);
  u += 0x7fffu + ((u >> 16) & 1u);
  return (u16)(u >> 16);
}

static constexpr int  B_ = 2, N_ = 2048, C_ = 1024, H_ = 8, DH_ = 128;
static constexpr long SZ_IN = (long)B_ * N_ * C_;  // 4,194,304 elems
static constexpr long SZ_W  = (long)C_ * C_;       // 1,048,576 elems

// ---------------------------------------------------------------------------
// Fused cast kernel: y=0/1 -> input fp32->bf16 cast; y=2 -> weight
// cast+transpose (x<1024: matrix z=x>>8, 64x64 tile = x&255). One launch
// instead of two (fewer launch gaps; paths are block-uniform).
// ---------------------------------------------------------------------------
__global__ void k_cast(const float* __restrict__ q, const float* __restrict__ kv,
                       const float* __restrict__ W0, const float* __restrict__ W1,
                       const float* __restrict__ W2, const float* __restrict__ W3,
                       u16* __restrict__ qb, u16* __restrict__ kvb,
                       u16* __restrict__ WT)
{
  __shared__ u16 t[64][65];
  int tid = threadIdx.x;
  if (blockIdx.y < 2) {
    const float* src = blockIdx.y ? kv : q;
    u16* dst = blockIdx.y ? kvb : qb;
    long i = ((long)blockIdx.x * 256 + tid) * 8;
    float4 a = *(const float4*)(src + i);
    float4 b = *(const float4*)(src + i + 4);
    uint4 v;
    v.x = f2bf(a.x) | ((unsigned)f2bf(a.y) << 16);
    v.y = f2bf(a.z) | ((unsigned)f2bf(a.w) << 16);
    v.z = f2bf(b.x) | ((unsigned)f2bf(b.y) << 16);
    v.w = f2bf(b.z) | ((unsigned)f2bf(b.w) << 16);
    *(uint4*)(dst + i) = v;
    return;
  }
  int x = blockIdx.x;
  if (x >= 1024) return;
  int z = x >> 8, tile = x & 255;
  const float* W = (z == 0) ? W0 : (z == 1) ? W1 : (z == 2) ? W2 : W3;
  u16* dst = WT + (long)z * SZ_W;
  int n0 = (tile & 15) * 64, k0 = (tile >> 4) * 64;
#pragma unroll
  for (int r = 0; r < 4; ++r) {
    int slot = r * 256 + tid;
    int row = slot >> 4, c4 = slot & 15;
    float4 a = *(const float4*)(W + (long)(k0 + row) * 1024 + n0 + c4 * 4);
    t[c4*4+0][row] = f2bf(a.x);
    t[c4*4+1][row] = f2bf(a.y);
    t[c4*4+2][row] = f2bf(a.z);
    t[c4*4+3][row] = f2bf(a.w);
  }
  __syncthreads();
#pragma unroll
  for (int r = 0; r < 4; ++r) {
    int slot = r * 256 + tid;
    int row = slot >> 4, c4 = slot & 15;
    uint2 v;
    v.x = t[row][c4*4+0] | ((unsigned)t[row][c4*4+1] << 16);
    v.y = t[row][c4*4+2] | ((unsigned)t[row][c4*4+3] << 16);
    *(uint2*)(dst + (long)(n0 + row) * 1024 + k0 + c4 * 4) = v;
  }
}

// ---------------------------------------------------------------------------
// m97-style GEMM mainloop with XOR bank swizzle (round-2-proven, unchanged).
// ---------------------------------------------------------------------------
__device__ __forceinline__ void gemm_main_128x128(
    const u16* __restrict__ A, const u16* __restrict__ BT,
    u16* lA, u16* lB, int m0, int n0, int tid, f32x4 acc[4][4])
{
  int w = tid >> 6, l = tid & 63, quad = l >> 4, lm = l & 15;
  int wm = w >> 1, wn = w & 1;
  int srow = tid >> 2, schunk = tid & 3;
  int sxw = (srow >> 1) & 3;
  int sxr = (lm >> 1) & 3;
  const u16* Ag = A + (long)(m0 + srow) * 1024 + (schunk ^ sxw) * 8;
  const u16* Bg = BT + (long)(n0 + srow) * 1024 + (schunk ^ sxw) * 8;
  u16* lAw = lA + w * 512;
  u16* lBw = lB + w * 512;
  for (int kb = 0; kb < 32; ++kb) {
    const u16* Agk = Ag + kb * 32;
    const u16* Bgk = Bg + kb * 32;
    __builtin_amdgcn_global_load_lds(AS1(Agk),           AS3(lAw),        16, 0, 0);
    __builtin_amdgcn_global_load_lds(AS1(Agk + 64*1024), AS3(lAw + 2048), 16, 0, 0);
    __builtin_amdgcn_global_load_lds(AS1(Bgk),           AS3(lBw),        16, 0, 0);
    __builtin_amdgcn_global_load_lds(AS1(Bgk + 64*1024), AS3(lBw + 2048), 16, 0, 0);
    __syncthreads();
    bf16x8 af[4], bfr[4];
#pragma unroll
    for (int mi = 0; mi < 4; ++mi)
      af[mi] = *(const bf16x8*)(lA + (wm*64 + mi*16 + lm)*32 + ((quad ^ sxr))*8);
#pragma unroll
    for (int ni = 0; ni < 4; ++ni)
      bfr[ni] = *(const bf16x8*)(lB + (wn*64 + ni*16 + lm)*32 + ((quad ^ sxr))*8);
#pragma unroll
    for (int mi = 0; mi < 4; ++mi)
#pragma unroll
      for (int ni = 0; ni < 4; ++ni)
        acc[mi][ni] = __builtin_amdgcn_mfma_f32_16x16x32_bf16(af[mi], bfr[ni], acc[mi][ni], 0, 0, 0);
    __syncthreads();
  }
}

// ---------------------------------------------------------------------------
// QKV projection v2 (unchanged, r6/r7-proven).
// ---------------------------------------------------------------------------
__global__ __launch_bounds__(256, 3)
void k_gemm_qkv(const u16* __restrict__ qb, const u16* __restrict__ kvb,
                const u16* __restrict__ wt,
                const float* __restrict__ bq, const float* __restrict__ bk,
                const float* __restrict__ bv,
                u16* __restrict__ Qb, u16* __restrict__ Kb, u16* __restrict__ VTb)
{
  __shared__ u16 lA[4096], lB[4096];
  int tid = threadIdx.x;
  int z = blockIdx.z;
  f32x4 acc[4][4] = {};
  int w = tid >> 6, l = tid & 63, quad = l >> 4, lm = l & 15;
  int wm = w >> 1, wn = w & 1;

  if (z == 2) {
    int m0 = blockIdx.y * 128, n0 = blockIdx.x * 128;
    gemm_main_128x128(kvb, wt + 2 * SZ_W, lA, lB, m0, n0, tid, acc);
#pragma unroll
    for (int ni = 0; ni < 4; ++ni) {
      int n = n0 + wn*64 + ni*16 + lm;       // channel
      float bb = bv[n];
      int h = n >> 7, dd = n & 127;
#pragma unroll
      for (int mi = 0; mi < 4; ++mi) {
        int mbase = m0 + wm*64 + mi*16 + quad*4;  // token (4 consecutive)
        int bidx = mbase >> 11, nn = mbase & 2047;
        u16 o0 = f2bf(acc[mi][ni][0] + bb), o1 = f2bf(acc[mi][ni][1] + bb);
        u16 o2 = f2bf(acc[mi][ni][2] + bb), o3 = f2bf(acc[mi][ni][3] + bb);
        uint2 v; v.x = o0 | ((unsigned)o1 << 16); v.y = o2 | ((unsigned)o3 << 16);
        *(uint2*)(VTb + ((long)(bidx*8 + h)*128 + dd)*2048 + nn) = v;
      }
    }
  } else {
    const u16* X = (z == 0) ? qb : kvb;
    const float* bias = (z == 0) ? bq : bk;
    u16* dst = (z == 0) ? Qb : Kb;
    float scale = (z == 0) ? 0.08838834764831845f : 1.0f;  // fold 1/sqrt(128)
    int m0 = blockIdx.x * 128, n0 = blockIdx.y * 128;
    gemm_main_128x128(wt + (long)z * SZ_W, X, lA, lB, m0, n0, tid, acc);
#pragma unroll
    for (int mi = 0; mi < 4; ++mi) {
      int chb = m0 + wm*64 + mi*16 + quad*4;   // channel base (4 consecutive)
      int h = chb >> 7, d = chb & 127;
      float4 bb = *(const float4*)(bias + chb);
#pragma unroll
      for (int ni = 0; ni < 4; ++ni) {
        int tok = n0 + wn*64 + ni*16 + lm;
        int bidx = tok >> 11, nn = tok & 2047;
        u16 o0 = f2bf((acc[mi][ni][0] + bb.x) * scale);
        u16 o1 = f2bf((acc[mi][ni][1] + bb.y) * scale);
        u16 o2 = f2bf((acc[mi][ni][2] + bb.z) * scale);
        u16 o3 = f2bf((acc[mi][ni][3] + bb.w) * scale);
        uint2 v; v.x = o0 | ((unsigned)o1 << 16); v.y = o2 | ((unsigned)o3 << 16);
        *(uint2*)(dst + ((long)(bidx*8 + h)*2048 + nn)*128 + d) = v;
      }
    }
  }
}

// ---------------------------------------------------------------------------
// Flash attention v10 — v8 structure + cross-tile PV pipeline (T15).
//
// v8 (88.7us): MfmaUtil 15.4, VALUBusy 22.7, HBM 3%, Occ 20.5 -> latency-
// bound on the per-tile serial chain: kf lgkm wait -> QK^T -> exp -> P write
// -> P read round-trip -> PV. ~1663 cyc/block-tile, MFMA only ~310.
// v9 (144us) proved occupancy is NOT the lever: 2x waves with halved
// per-wave work doubled duplicated kf/V traffic and halved ILP -> slower.
//
// v10 keeps v8's 2-wave blocks and per-wave work EXACTLY, but breaks the
// serial chain: PV(t) operands (pfP, vfP) are read/loaded in iteration t and
// consumed in iteration t+1. The P LDS round-trip and the V L2 latency are
// drained for free by the next barrier; PV(t-1)'s 16 MFMAs issue under
// QK^T(t)'s kf lgkm wait (kf reads issued first). Epilogue does PV(31).
// LDS u16 layout unchanged: bufK [0,16384) (kh*2+buf)*4096 | lP
// [16384,18432) | lStat [18432,18560). lO (f32, 16 KB) overlays bufK.
// ---------------------------------------------------------------------------
__global__ __launch_bounds__(128, 2)
void k_attn(const u16* __restrict__ Qb, const u16* __restrict__ Kb,
            const u16* __restrict__ VTb, u16* __restrict__ Sout)
{
  __shared__ u16 smem[18560];   // 37120 B -> 4 blocks/CU
  u16*   lP    = smem + 16384;
  float* lStat = (float*)(smem + 18432);  // [2 waves][32 q]

  int tid = threadIdx.x;
  int w = tid >> 6, l = tid & 63, quad = l >> 4, lm = l & 15;
  int kh = w;                      // wave = key half
  int bh = blockIdx.x;             // XCD = bh % 8
  int q0 = blockIdx.y * 32;
  const u16* Qg = Qb + ((long)bh * 2048 + q0) * 128;
  const u16* Kg = Kb + (long)bh * 2048 * 128;
  const u16* Vg = VTb + (long)bh * 128 * 2048;
  u16* lPw = lP + w * 1024;

  // register-resident Q (32 q-rows, DH=128), scale pre-folded at projection
  bf16x8 qf[2][4];
#pragma unroll
  for (int mi = 0; mi < 2; ++mi)
#pragma unroll
    for (int kk = 0; kk < 4; ++kk)
      qf[mi][kk] = *(const bf16x8*)(Qg + (long)(mi*16 + lm)*128 + kk*32 + quad*8);

  f32x4 accO[2][8] = {};
  float sumP[2][4] = {};

  // K tile staging: 32 keys x 128 d = 512 x 16B chunks; own wave stages its
  // half's tile (8 DMA insts). Chunk swizzle c^(r&7) -> kf reads 2-way max.
  auto stage = [&](int tt) {
    u16* dstb = smem + (kh*2 + (tt & 1)) * 4096;
#pragma unroll
    for (int j = 0; j < 8; ++j) {
      int s = j*64 + l;
      int r = s >> 4, c = s & 15;
      __builtin_amdgcn_global_load_lds(
          AS1(Kg + (long)(kh*1024 + tt*32 + r)*128 + ((c ^ (r & 7)) * 8)),
          AS3(dstb + j*512), 16, 0, 0);
    }
  };

  stage(0);

  bf16x8 pfP[2];   // P(t-1) A-frags, read from LDS at end of iter t-1
  bf16x8 vfP[8];   // V(t-1) B-frags, loaded in iter t-1

#pragma unroll 1
  for (int t = 0; t < 32; ++t) {
    __syncthreads();          // drains stage(t) DMA + pfP read + vfP loads
    stage(t + 1);             // t=31: prefetch runs past this head's K (ws, benign)

    // kf reads issued FIRST so PV(t-1) executes under their lgkm latency
    const u16* bk = smem + (kh*2 + (t & 1)) * 4096;
    bf16x8 kfr[8];
#pragma unroll
    for (int kk = 0; kk < 4; ++kk)
#pragma unroll
      for (int ni = 0; ni < 2; ++ni)
        kfr[kk*2+ni] = *(const bf16x8*)(bk + ((ni*16 + lm)*16 + (((kk*4 + quad) ^ (lm & 7))))*8);

    // O += P(t-1) V(t-1): all operands register-resident since last iter
    if (t > 0) {
#pragma unroll
      for (int ni = 0; ni < 8; ++ni)
#pragma unroll
        for (int mi = 0; mi < 2; ++mi)
          accO[mi][ni] = __builtin_amdgcn_mfma_f32_16x16x32_bf16(pfP[mi], vfP[ni], accO[mi][ni], 0, 0, 0);
    }

    int k0 = kh*1024 + t*32;
    // V(t) fragments direct from global (L2-resident), consumed next iter;
    // latency absorbed by the next barrier's vmcnt drain.
#pragma unroll
    for (int ni = 0; ni < 8; ++ni)
      vfP[ni] = *(const bf16x8*)(Vg + (long)(ni*16 + lm)*2048 + k0 + quad*8);

    // QK^T: 32q x 32k from the PREFETCHED LDS buffer
    f32x4 accS[2][2] = {};
#pragma unroll
    for (int kk = 0; kk < 4; ++kk)
#pragma unroll
      for (int ni = 0; ni < 2; ++ni)
#pragma unroll
        for (int mi = 0; mi < 2; ++mi)
          accS[mi][ni] = __builtin_amdgcn_mfma_f32_16x16x32_bf16(qf[mi][kk], kfr[kk*2+ni], accS[mi][ni], 0, 0, 0);

    // no-max softmax: p = exp(s); per-lane partial sums; P -> swizzled LDS
#pragma unroll
    for (int mi = 0; mi < 2; ++mi)
#pragma unroll
      for (int r = 0; r < 4; ++r) {
        int R = mi*16 + quad*4 + r;
        int xr = (quad*2 + (r >> 1)) & 3;
#pragma unroll
        for (int ni = 0; ni < 2; ++ni) {
          float p = __expf(accS[mi][ni][r]);
          sumP[mi][r] += p;
          int ch = ni*2 + (lm >> 3);
          lPw[(R*4 + (ch ^ xr))*8 + (lm & 7)] = f2bf(p);
        }
      }

    // P(t) A-frags for NEXT iteration (latency hidden; own wave's region,
    // LDS unit processes the wave's write->read in order)
#pragma unroll
    for (int mi = 0; mi < 2; ++mi)
      pfP[mi] = *(const bf16x8*)(lPw + ((mi*16 + lm)*4 + (quad ^ ((lm >> 1) & 3)))*8);
  }

  // epilogue: PV(31)
#pragma unroll
  for (int ni = 0; ni < 8; ++ni)
#pragma unroll
    for (int mi = 0; mi < 2; ++mi)
      accO[mi][ni] = __builtin_amdgcn_mfma_f32_16x16x32_bf16(pfP[mi], vfP[ni], accO[mi][ni], 0, 0, 0);

  // ---- row-sum reduce (16 col-lanes per row) + publish stats ----
#pragma unroll
  for (int mi = 0; mi < 2; ++mi)
#pragma unroll
    for (int r = 0; r < 4; ++r) {
      float s = sumP[mi][r];
      s += __shfl_xor(s, 1);
      s += __shfl_xor(s, 2);
      s += __shfl_xor(s, 4);
      s += __shfl_xor(s, 8);
      lStat[w*32 + mi*16 + quad*4 + r] = s;   // 16 lanes same val: benign
    }

  // ---- 2-wave merge: kh=1 parks unnormalized O in LDS, kh=0 combines ----
  float* lO = (float*)smem;   // [32 q][128 d] f32 = 16 KB, overlays bufK
  __syncthreads();            // drains stage(32) DMA; lStat visible
  if (w == 1) {
#pragma unroll
    for (int mi = 0; mi < 2; ++mi)
#pragma unroll
      for (int ni = 0; ni < 8; ++ni)
#pragma unroll
        for (int r = 0; r < 4; ++r)
          lO[(mi*16 + quad*4 + r)*128 + ni*16 + lm] = accO[mi][ni][r];
  }
  __syncthreads();
  if (w == 0) {
    int b = bh >> 3, h = bh & 7;
#pragma unroll
    for (int mi = 0; mi < 2; ++mi)
#pragma unroll
      for (int r = 0; r < 4; ++r) {
        int R = mi*16 + quad*4 + r;
        float linv = 1.f / (lStat[R] + lStat[32 + R]);
#pragma unroll
        for (int ni = 0; ni < 8; ++ni) {
          float v = (accO[mi][ni][r] + lO[R*128 + ni*16 + lm]) * linv;
          Sout[((long)(b*2048 + q0 + R))*1024 + h*128 + ni*16 + lm] = f2bf(v);
        }
      }
  }
}

// ---------------------------------------------------------------------------
// Output projection v2 (unchanged, r6/r7-proven).
// ---------------------------------------------------------------------------
__global__ __launch_bounds__(256, 3)
void k_gemm_out(const u16* __restrict__ S, const u16* __restrict__ WoT,
                const float* __restrict__ bo, float* __restrict__ out)
{
  __shared__ u16 lA[4096], lB[4096];
  int tid = threadIdx.x;
  int m0 = blockIdx.x * 128, n0 = blockIdx.y * 128;   // m = channel, n = token
  f32x4 acc[4][4] = {};
  gemm_main_128x128(WoT, S, lA, lB, m0, n0, tid, acc);

  int w = tid >> 6, l = tid & 63, quad = l >> 4, lm = l & 15;
  int wm = w >> 1, wn = w & 1;
#pragma unroll
  for (int mi = 0; mi < 4; ++mi) {
    int chb = m0 + wm*64 + mi*16 + quad*4;   // 4 consecutive channels
    float4 bb = *(const float4*)(bo + chb);
#pragma unroll
    for (int ni = 0; ni < 4; ++ni) {
      int tok = n0 + wn*64 + ni*16 + lm;
      float4 v;
      v.x = acc[mi][ni][0] + bb.x;
      v.y = acc[mi][ni][1] + bb.y;
      v.z = acc[mi][ni][2] + bb.z;
      v.w = acc[mi][ni][3] + bb.w;
      *(float4*)(out + (long)tok * 1024 + chb) = v;
    }
  }
}

// ---------------------------------------------------------------------------
// ws layout (u16 elems), 48 MiB: ABUF (q_bf16, reused for summed), KVB,
// WT 4x, Qb/Kb [b][h][n][d], VTb [b][h][d][n]
// ---------------------------------------------------------------------------
extern "C" void kernel_launch(void* const* d_in, const int* in_sizes, int n_in,
                              void* d_out, int out_size, void* d_ws, size_t ws_size,
                              hipStream_t stream)
{
  const float* inq  = (const float*)d_in[0];
  const float* inkv = (const float*)d_in[1];
  const float* Wq = (const float*)d_in[2];
  const float* bq = (const float*)d_in[3];
  const float* Wk = (const float*)d_in[4];
  const float* bk = (const float*)d_in[5];
  const float* Wv = (const float*)d_in[6];
  const float* bv = (const float*)d_in[7];
  const float* Wo = (const float*)d_in[8];
  const float* bo = (const float*)d_in[9];

  u16* ws   = (u16*)d_ws;
  u16* ABUF = ws;
  u16* KVB  = ws + SZ_IN;
  u16* WT   = ws + 2 * SZ_IN;
  u16* Qb   = WT + 4 * SZ_W;
  u16* Kb   = Qb + SZ_IN;
  u16* VTb  = Kb + SZ_IN;

  k_cast    <<<dim3(2048, 3),   256, 0, stream>>>(inq, inkv, Wq, Wk, Wv, Wo, ABUF, KVB, WT);
  k_gemm_qkv<<<dim3(8, 32, 3),  256, 0, stream>>>(ABUF, KVB, WT, bq, bk, bv, Qb, Kb, VTb);
  k_attn    <<<dim3(16, 64),    128, 0, stream>>>(Qb, Kb, VTb, ABUF);
  k_gemm_out<<<dim3(8, 32),     256, 0, stream>>>(ABUF, WT + 3 * SZ_W, bo, (float*)d_out);
}

// Round 3
// 219.543 us; speedup vs baseline: 1.3586x; 1.1064x over previous
//
#include <hip/hip_runtime.h>

typedef unsigned short u16;
typedef __bf16 bf16;
typedef __attribute__((ext_vector_type(8))) __bf16 bf16x8;  // MFMA A/B frag (4 VGPRs)
typedef __attribute__((ext_vector_type(4))) float f32x4;    // MFMA C/D frag

#define AS1(p) ((const __attribute__((address_space(1))) void*)(p))
#define AS3(p) ((__attribute__((address_space(3))) void*)(p))

__device__ __forceinline__ u16 f2bf(float f) {
  unsigned u = __builtin_bit_cast(unsigned, f);
  u += 0x7fffu + ((u >> 16) & 1u);
  return (u16)(u >> 16);
}

static constexpr int  B_ = 2, N_ = 2048, C_ = 1024, H_ = 8, DH_ = 128;
static constexpr long SZ_IN = (long)B_ * N_ * C_;  // 4,194,304 elems
static constexpr long SZ_W  = (long)C_ * C_;       // 1,048,576 elems

// ---------------------------------------------------------------------------
// Fused cast kernel: y=0/1 -> input fp32->bf16 cast; y=2 -> weight
// cast+transpose (x<1024: matrix z=x>>8, 64x64 tile = x&255). One launch
// instead of two (fewer launch gaps; paths are block-uniform).
// ---------------------------------------------------------------------------
__global__ void k_cast(const float* __restrict__ q, const float* __restrict__ kv,
                       const float* __restrict__ W0, const float* __restrict__ W1,
                       const float* __restrict__ W2, const float* __restrict__ W3,
                       u16* __restrict__ qb, u16* __restrict__ kvb,
                       u16* __restrict__ WT)
{
  __shared__ u16 t[64][65];
  int tid = threadIdx.x;
  if (blockIdx.y < 2) {
    const float* src = blockIdx.y ? kv : q;
    u16* dst = blockIdx.y ? kvb : qb;
    long i = ((long)blockIdx.x * 256 + tid) * 8;
    float4 a = *(const float4*)(src + i);
    float4 b = *(const float4*)(src + i + 4);
    uint4 v;
    v.x = f2bf(a.x) | ((unsigned)f2bf(a.y) << 16);
    v.y = f2bf(a.z) | ((unsigned)f2bf(a.w) << 16);
    v.z = f2bf(b.x) | ((unsigned)f2bf(b.y) << 16);
    v.w = f2bf(b.z) | ((unsigned)f2bf(b.w) << 16);
    *(uint4*)(dst + i) = v;
    return;
  }
  int x = blockIdx.x;
  if (x >= 1024) return;
  int z = x >> 8, tile = x & 255;
  const float* W = (z == 0) ? W0 : (z == 1) ? W1 : (z == 2) ? W2 : W3;
  u16* dst = WT + (long)z * SZ_W;
  int n0 = (tile & 15) * 64, k0 = (tile >> 4) * 64;
#pragma unroll
  for (int r = 0; r < 4; ++r) {
    int slot = r * 256 + tid;
    int row = slot >> 4, c4 = slot & 15;
    float4 a = *(const float4*)(W + (long)(k0 + row) * 1024 + n0 + c4 * 4);
    t[c4*4+0][row] = f2bf(a.x);
    t[c4*4+1][row] = f2bf(a.y);
    t[c4*4+2][row] = f2bf(a.z);
    t[c4*4+3][row] = f2bf(a.w);
  }
  __syncthreads();
#pragma unroll
  for (int r = 0; r < 4; ++r) {
    int slot = r * 256 + tid;
    int row = slot >> 4, c4 = slot & 15;
    uint2 v;
    v.x = t[row][c4*4+0] | ((unsigned)t[row][c4*4+1] << 16);
    v.y = t[row][c4*4+2] | ((unsigned)t[row][c4*4+3] << 16);
    *(uint2*)(dst + (long)(n0 + row) * 1024 + k0 + c4 * 4) = v;
  }
}

// ---------------------------------------------------------------------------
// m97-style GEMM mainloop with XOR bank swizzle (round-2-proven, unchanged).
// ---------------------------------------------------------------------------
__device__ __forceinline__ void gemm_main_128x128(
    const u16* __restrict__ A, const u16* __restrict__ BT,
    u16* lA, u16* lB, int m0, int n0, int tid, f32x4 acc[4][4])
{
  int w = tid >> 6, l = tid & 63, quad = l >> 4, lm = l & 15;
  int wm = w >> 1, wn = w & 1;
  int srow = tid >> 2, schunk = tid & 3;
  int sxw = (srow >> 1) & 3;
  int sxr = (lm >> 1) & 3;
  const u16* Ag = A + (long)(m0 + srow) * 1024 + (schunk ^ sxw) * 8;
  const u16* Bg = BT + (long)(n0 + srow) * 1024 + (schunk ^ sxw) * 8;
  u16* lAw = lA + w * 512;
  u16* lBw = lB + w * 512;
  for (int kb = 0; kb < 32; ++kb) {
    const u16* Agk = Ag + kb * 32;
    const u16* Bgk = Bg + kb * 32;
    __builtin_amdgcn_global_load_lds(AS1(Agk),           AS3(lAw),        16, 0, 0);
    __builtin_amdgcn_global_load_lds(AS1(Agk + 64*1024), AS3(lAw + 2048), 16, 0, 0);
    __builtin_amdgcn_global_load_lds(AS1(Bgk),           AS3(lBw),        16, 0, 0);
    __builtin_amdgcn_global_load_lds(AS1(Bgk + 64*1024), AS3(lBw + 2048), 16, 0, 0);
    __syncthreads();
    bf16x8 af[4], bfr[4];
#pragma unroll
    for (int mi = 0; mi < 4; ++mi)
      af[mi] = *(const bf16x8*)(lA + (wm*64 + mi*16 + lm)*32 + ((quad ^ sxr))*8);
#pragma unroll
    for (int ni = 0; ni < 4; ++ni)
      bfr[ni] = *(const bf16x8*)(lB + (wn*64 + ni*16 + lm)*32 + ((quad ^ sxr))*8);
#pragma unroll
    for (int mi = 0; mi < 4; ++mi)
#pragma unroll
      for (int ni = 0; ni < 4; ++ni)
        acc[mi][ni] = __builtin_amdgcn_mfma_f32_16x16x32_bf16(af[mi], bfr[ni], acc[mi][ni], 0, 0, 0);
    __syncthreads();
  }
}

// ---------------------------------------------------------------------------
// QKV projection v2 (unchanged, r6/r7-proven).
// ---------------------------------------------------------------------------
__global__ __launch_bounds__(256, 3)
void k_gemm_qkv(const u16* __restrict__ qb, const u16* __restrict__ kvb,
                const u16* __restrict__ wt,
                const float* __restrict__ bq, const float* __restrict__ bk,
                const float* __restrict__ bv,
                u16* __restrict__ Qb, u16* __restrict__ Kb, u16* __restrict__ VTb)
{
  __shared__ u16 lA[4096], lB[4096];
  int tid = threadIdx.x;
  int z = blockIdx.z;
  f32x4 acc[4][4] = {};
  int w = tid >> 6, l = tid & 63, quad = l >> 4, lm = l & 15;
  int wm = w >> 1, wn = w & 1;

  if (z == 2) {
    int m0 = blockIdx.y * 128, n0 = blockIdx.x * 128;
    gemm_main_128x128(kvb, wt + 2 * SZ_W, lA, lB, m0, n0, tid, acc);
#pragma unroll
    for (int ni = 0; ni < 4; ++ni) {
      int n = n0 + wn*64 + ni*16 + lm;       // channel
      float bb = bv[n];
      int h = n >> 7, dd = n & 127;
#pragma unroll
      for (int mi = 0; mi < 4; ++mi) {
        int mbase = m0 + wm*64 + mi*16 + quad*4;  // token (4 consecutive)
        int bidx = mbase >> 11, nn = mbase & 2047;
        u16 o0 = f2bf(acc[mi][ni][0] + bb), o1 = f2bf(acc[mi][ni][1] + bb);
        u16 o2 = f2bf(acc[mi][ni][2] + bb), o3 = f2bf(acc[mi][ni][3] + bb);
        uint2 v; v.x = o0 | ((unsigned)o1 << 16); v.y = o2 | ((unsigned)o3 << 16);
        *(uint2*)(VTb + ((long)(bidx*8 + h)*128 + dd)*2048 + nn) = v;
      }
    }
  } else {
    const u16* X = (z == 0) ? qb : kvb;
    const float* bias = (z == 0) ? bq : bk;
    u16* dst = (z == 0) ? Qb : Kb;
    float scale = (z == 0) ? 0.08838834764831845f : 1.0f;  // fold 1/sqrt(128)
    int m0 = blockIdx.x * 128, n0 = blockIdx.y * 128;
    gemm_main_128x128(wt + (long)z * SZ_W, X, lA, lB, m0, n0, tid, acc);
#pragma unroll
    for (int mi = 0; mi < 4; ++mi) {
      int chb = m0 + wm*64 + mi*16 + quad*4;   // channel base (4 consecutive)
      int h = chb >> 7, d = chb & 127;
      float4 bb = *(const float4*)(bias + chb);
#pragma unroll
      for (int ni = 0; ni < 4; ++ni) {
        int tok = n0 + wn*64 + ni*16 + lm;
        int bidx = tok >> 11, nn = tok & 2047;
        u16 o0 = f2bf((acc[mi][ni][0] + bb.x) * scale);
        u16 o1 = f2bf((acc[mi][ni][1] + bb.y) * scale);
        u16 o2 = f2bf((acc[mi][ni][2] + bb.z) * scale);
        u16 o3 = f2bf((acc[mi][ni][3] + bb.w) * scale);
        uint2 v; v.x = o0 | ((unsigned)o1 << 16); v.y = o2 | ((unsigned)o3 << 16);
        *(uint2*)(dst + ((long)(bidx*8 + h)*2048 + nn)*128 + d) = v;
      }
    }
  }
}

// ---------------------------------------------------------------------------
// Flash attention v11 — L2/TA traffic reduction via QBLK=128 shared tiles.
//
// Traffic theory from v8/v9/v10: per-CU bytes through TA per iteration-period
// is invariant at ~18-19 B/cyc/CU (v8: 128KB/6727cy; v9: 192KB/10870cy; v10
// == v8), right at the per-CU streaming ceiling (m13: 24.6 B/cyc). The kernel
// is bound by vector-memory request throughput, NOT latency (v10's chain-
// break was neutral) and NOT occupancy (v9 hurt in proportion to traffic).
//
// v11 attacks bytes/MFMA: QBLK 32 -> 128. Grid (16 bh, 16 qb) = 256 blocks =
// 1/CU, 8 waves (512 thr), wave w owns q-rows qb*128+w*16..+16 over ALL 2048
// keys (64 tiles of 32). K AND V tiles are staged to LDS once per block and
// shared by all 8 waves (1 K-DMA + 1 V-DMA instr per wave per tile). Per-CU
// TA traffic drops 4x to the blocking minimum (K 512KB + V 512KB ~ 1MB).
// No key-split -> no lStat/lO merge epilogue at all.
// K LDS: v8's proven layout/swizzle (row*16chunks, chunk^=(row&7)).
// V LDS: row-pair layout [dd=d>>1][8 chunks], chunk c2=(d&1)*4+c, slot =
// c2^(dd&7); DMA dest stays lane-linear (swizzle applied to the GLOBAL src
// address, m173 pattern); vf ds_read_b128 lands 2-way conflict-free.
// LDS u16: bufK 2x4096 [0,8192) | bufV 2x4096 [8192,16384) | lP 8x512
// [16384,20480) = 40 KB.
// ---------------------------------------------------------------------------
__global__ __launch_bounds__(512, 2)
void k_attn(const u16* __restrict__ Qb, const u16* __restrict__ Kb,
            const u16* __restrict__ VTb, u16* __restrict__ Sout)
{
  __shared__ u16 smem[20480];   // 40 KB
  u16* lP = smem + 16384;

  int tid = threadIdx.x;
  int w = tid >> 6, l = tid & 63, quad = l >> 4, lm = l & 15;
  int bh = blockIdx.x;             // XCD = bh % 8 -> 2 bh per XCD L2 (2 MB K+V)
  int q0 = blockIdx.y * 128 + w * 16;
  const u16* Qg = Qb + ((long)bh * 2048 + q0) * 128;
  const u16* Kg = Kb + (long)bh * 2048 * 128;
  const u16* Vg = VTb + (long)bh * 128 * 2048;
  u16* lPw = lP + w * 512;

  // register-resident Q (16 q-rows, DH=128), scale pre-folded at projection
  bf16x8 qf[4];
#pragma unroll
  for (int kk = 0; kk < 4; ++kk)
    qf[kk] = *(const bf16x8*)(Qg + (long)lm * 128 + kk*32 + quad*8);

  f32x4 accO[8] = {};
  float sumP[4] = {};

  // Cooperative staging: per tile, wave w issues 1 K-DMA (rows w*4..w*4+4,
  // 16 chunks each, src chunk ^= row&7) and 1 V-DMA (row-pair layout, src
  // pre-swizzled so LDS dest is lane-linear).
  auto stage = [&](int tt) {
    int buf = (tt & 1) * 4096;
    {
      int r = w*4 + (l >> 4);          // local key row 0..31
      int c = l & 15;
      __builtin_amdgcn_global_load_lds(
          AS1(Kg + (long)(tt*32 + r)*128 + ((c ^ (r & 7)) * 8)),
          AS3(smem + buf + w*512), 16, 0, 0);
    }
    {
      int dd = w*8 + (l >> 3);         // d row-pair 0..63
      int c2 = (l & 7) ^ (l >> 3);     // logical chunk in row-pair
      int d  = dd*2 + (c2 >> 2);       // d row 0..127
      int c  = c2 & 3;                 // chunk within d row
      __builtin_amdgcn_global_load_lds(
          AS1(Vg + (long)d*2048 + tt*32 + c*8),
          AS3(smem + 8192 + buf + w*512), 16, 0, 0);
    }
  };

  stage(0);

#pragma unroll 1
  for (int t = 0; t < 64; ++t) {
    __syncthreads();          // drains stage(t) DMA; WAR-protects buf (t+1)&1
    if (t < 63) stage(t + 1);

    const u16* bK = smem + (t & 1) * 4096;
    const u16* bV = smem + 8192 + (t & 1) * 4096;

    // QK^T: 16q x 32k from shared LDS K tile
    f32x4 accS[2] = {};
#pragma unroll
    for (int kk = 0; kk < 4; ++kk)
#pragma unroll
      for (int ni = 0; ni < 2; ++ni) {
        bf16x8 kf = *(const bf16x8*)(bK + (ni*16 + lm)*128 + (((kk*4 + quad) ^ (lm & 7)))*8);
        accS[ni] = __builtin_amdgcn_mfma_f32_16x16x32_bf16(qf[kk], kf, accS[ni], 0, 0, 0);
      }

    // V B-frags from shared LDS V tile (2-way conflict-free by construction)
    bf16x8 vf[8];
#pragma unroll
    for (int ni = 0; ni < 8; ++ni) {
      int dd = ni*8 + (lm >> 1);
      int slot = (((lm & 1)*4 + quad) ^ (lm >> 1));
      vf[ni] = *(const bf16x8*)(bV + dd*64 + slot*8);
    }

    // no-max softmax: p = exp(s); per-lane partial sums; P -> swizzled LDS
#pragma unroll
    for (int r = 0; r < 4; ++r) {
      int R = quad*4 + r;
      int xr = (R >> 1) & 3;
#pragma unroll
      for (int ni = 0; ni < 2; ++ni) {
        float p = __expf(accS[ni][r]);
        sumP[r] += p;
        int ch = ni*2 + (lm >> 3);
        lPw[(R*4 + (ch ^ xr))*8 + (lm & 7)] = f2bf(p);
      }
    }

    // P A-frag (own wave's LDS region; compiler inserts lgkmcnt wait)
    bf16x8 pf = *(const bf16x8*)(lPw + (lm*4 + (quad ^ ((lm >> 1) & 3)))*8);

    // O += P V
#pragma unroll
    for (int ni = 0; ni < 8; ++ni)
      accO[ni] = __builtin_amdgcn_mfma_f32_16x16x32_bf16(pf, vf[ni], accO[ni], 0, 0, 0);
  }

  // ---- row-sum reduce (16 col-lanes per row) + normalize + store ----
  // Each wave owns its 16 rows completely: no cross-wave merge needed.
  int b = bh >> 3, h = bh & 7;
#pragma unroll
  for (int r = 0; r < 4; ++r) {
    float s = sumP[r];
    s += __shfl_xor(s, 1);
    s += __shfl_xor(s, 2);
    s += __shfl_xor(s, 4);
    s += __shfl_xor(s, 8);
    float linv = 1.f / s;
#pragma unroll
    for (int ni = 0; ni < 8; ++ni) {
      float v = accO[ni][r] * linv;
      Sout[((long)(b*2048 + q0 + quad*4 + r))*1024 + h*128 + ni*16 + lm] = f2bf(v);
    }
  }
}

// ---------------------------------------------------------------------------
// Output projection v2 (unchanged, r6/r7-proven).
// ---------------------------------------------------------------------------
__global__ __launch_bounds__(256, 3)
void k_gemm_out(const u16* __restrict__ S, const u16* __restrict__ WoT,
                const float* __restrict__ bo, float* __restrict__ out)
{
  __shared__ u16 lA[4096], lB[4096];
  int tid = threadIdx.x;
  int m0 = blockIdx.x * 128, n0 = blockIdx.y * 128;   // m = channel, n = token
  f32x4 acc[4][4] = {};
  gemm_main_128x128(WoT, S, lA, lB, m0, n0, tid, acc);

  int w = tid >> 6, l = tid & 63, quad = l >> 4, lm = l & 15;
  int wm = w >> 1, wn = w & 1;
#pragma unroll
  for (int mi = 0; mi < 4; ++mi) {
    int chb = m0 + wm*64 + mi*16 + quad*4;   // 4 consecutive channels
    float4 bb = *(const float4*)(bo + chb);
#pragma unroll
    for (int ni = 0; ni < 4; ++ni) {
      int tok = n0 + wn*64 + ni*16 + lm;
      float4 v;
      v.x = acc[mi][ni][0] + bb.x;
      v.y = acc[mi][ni][1] + bb.y;
      v.z = acc[mi][ni][2] + bb.z;
      v.w = acc[mi][ni][3] + bb.w;
      *(float4*)(out + (long)tok * 1024 + chb) = v;
    }
  }
}

// ---------------------------------------------------------------------------
// ws layout (u16 elems), 48 MiB: ABUF (q_bf16, reused for summed), KVB,
// WT 4x, Qb/Kb [b][h][n][d], VTb [b][h][d][n]
// ---------------------------------------------------------------------------
extern "C" void kernel_launch(void* const* d_in, const int* in_sizes, int n_in,
                              void* d_out, int out_size, void* d_ws, size_t ws_size,
                              hipStream_t stream)
{
  const float* inq  = (const float*)d_in[0];
  const float* inkv = (const float*)d_in[1];
  const float* Wq = (const float*)d_in[2];
  const float* bq = (const float*)d_in[3];
  const float* Wk = (const float*)d_in[4];
  const float* bk = (const float*)d_in[5];
  const float* Wv = (const float*)d_in[6];
  const float* bv = (const float*)d_in[7];
  const float* Wo = (const float*)d_in[8];
  const float* bo = (const float*)d_in[9];

  u16* ws   = (u16*)d_ws;
  u16* ABUF = ws;
  u16* KVB  = ws + SZ_IN;
  u16* WT   = ws + 2 * SZ_IN;
  u16* Qb   = WT + 4 * SZ_W;
  u16* Kb   = Qb + SZ_IN;
  u16* VTb  = Kb + SZ_IN;

  k_cast    <<<dim3(2048, 3),   256, 0, stream>>>(inq, inkv, Wq, Wk, Wv, Wo, ABUF, KVB, WT);
  k_gemm_qkv<<<dim3(8, 32, 3),  256, 0, stream>>>(ABUF, KVB, WT, bq, bk, bv, Qb, Kb, VTb);
  k_attn    <<<dim3(16, 16),    512, 0, stream>>>(Qb, Kb, VTb, ABUF);
  k_gemm_out<<<dim3(8, 32),     256, 0, stream>>>(ABUF, WT + 3 * SZ_W, bo, (float*)d_out);
}